// Round 3
// baseline (1195.368 us; speedup 1.0000x reference)
//
#include <hip/hip_runtime.h>
#include <math.h>

using f32x4  = __attribute__((ext_vector_type(4))) float;
using bf16x8 = __attribute__((ext_vector_type(8))) short;
using u16x8  = __attribute__((ext_vector_type(8))) unsigned short;

constexpr int NFEAT = 512;
constexpr int NHID  = 256;
constexpr int NLAB  = 64;

__device__ __forceinline__ unsigned short f2bf(float f) {
    unsigned int u = __float_as_uint(f);
    u += 0x7FFFu + ((u >> 16) & 1u);          // RNE
    return (unsigned short)(u >> 16);
}
__device__ __forceinline__ float bf2f(unsigned short s) {
    return __uint_as_float(((unsigned int)s) << 16);
}
__device__ __forceinline__ void gload_lds16(const void* g, void* l) {
    __builtin_amdgcn_global_load_lds(
        (const __attribute__((address_space(1))) unsigned int*)g,
        (__attribute__((address_space(3))) unsigned int*)l, 16, 0, 0);
}

// ---------------- graph preprocessing ----------------

__global__ void hist_kernel(const int* __restrict__ col, int* __restrict__ hist, int E) {
    int e = blockIdx.x * blockDim.x + threadIdx.x;
    if (e < E) atomicAdd(&hist[col[e]], 1);
}

__global__ void dinv_kernel(const int* __restrict__ hist, float* __restrict__ dinv, int n) {
    int i = blockIdx.x * blockDim.x + threadIdx.x;
    if (i < n) dinv[i] = rsqrtf((float)hist[i] + 2.0f);  // deg = in-count + self-loop weight 2
}

// 3-phase scan
__global__ void scan1_kernel(const int* __restrict__ hist, int* __restrict__ start,
                             int* __restrict__ bsum, int n) {
    __shared__ int sm[1024];
    const int t = threadIdx.x;
    const int i = blockIdx.x * 1024 + t;
    int v = (i < n) ? hist[i] : 0;
    sm[t] = v;
    __syncthreads();
    for (int off = 1; off < 1024; off <<= 1) {
        int x2 = (t >= off) ? sm[t - off] : 0;
        __syncthreads();
        sm[t] += x2;
        __syncthreads();
    }
    start[i] = sm[t] - v;
    if (t == 1023) bsum[blockIdx.x] = sm[1023];
}

__global__ void scan2_kernel(int* __restrict__ bsum, int nb) {
    __shared__ int sm[1024];
    const int t = threadIdx.x;
    int v = (t < nb) ? bsum[t] : 0;
    sm[t] = v;
    __syncthreads();
    for (int off = 1; off < 1024; off <<= 1) {
        int x2 = (t >= off) ? sm[t - off] : 0;
        __syncthreads();
        sm[t] += x2;
        __syncthreads();
    }
    if (t < nb) bsum[t] = sm[t] - v;
}

__global__ void scan3_kernel(int* __restrict__ start, int* __restrict__ cursor,
                             const int* __restrict__ bsum, int P) {
    int i = blockIdx.x * blockDim.x + threadIdx.x;
    if (i < P) {
        int v = start[i] + bsum[i >> 10];
        start[i] = v;
        if (i < P - 1) cursor[i] = v;
    }
}

__global__ void scatter_kernel(const int* __restrict__ row, const int* __restrict__ col,
                               int* __restrict__ cursor, int* __restrict__ ssrc, int E) {
    int e = blockIdx.x * blockDim.x + threadIdx.x;
    if (e < E) {
        int r = row[e], c = col[e];
        int p = atomicAdd(&cursor[c], 1);
        ssrc[p] = r;
    }
}

__global__ void labflag_kernel(const int* __restrict__ idxl, const int* __restrict__ y,
                               int* __restrict__ flag, int L) {
    int k = blockIdx.x * blockDim.x + threadIdx.x;
    if (k < L) {
        int node = idxl[k];
        flag[node] = y[node];
    }
}

// ---------------- weight convert / transpose to bf16 ----------------

__global__ void convT_kernel(const float* __restrict__ in, unsigned short* __restrict__ out,
                             int K, int Nc) {
    int idx = blockIdx.x * blockDim.x + threadIdx.x;
    if (idx < K * Nc) {
        int n = idx / K, k = idx - n * K;
        out[idx] = f2bf(in[(size_t)k * Nc + n]);
    }
}

__global__ void conv_kernel(const float* __restrict__ in, unsigned short* __restrict__ out, int total) {
    int idx = blockIdx.x * blockDim.x + threadIdx.x;
    if (idx < total) out[idx] = f2bf(in[idx]);
}

// ---------------- bf16 MFMA GEMM: C[M,N] = A[M,K] @ Bt[N,K]^T ----------------
// BM=64, BN=256 (full N per col-block), BK=64, 4 waves each owning a 64x64
// output quadrant along N. global_load_lds w16 staging, source-side XOR
// swizzle (kg ^= row&7) -> conflict-free ds_read_b128.
// EPI: 0 = dinv-row-scale (layers 1,2); 1 = label-add + dinv-scale (layer 0);
//      2 = +bias, ELU (MLP hidden).  AF32: A is fp32 (layer 0 reads x).

template<int EPI, bool AF32>
__global__ __launch_bounds__(256) void mfma_gemm(
    const unsigned short* __restrict__ A, const float* __restrict__ Af,
    const unsigned short* __restrict__ Bt, unsigned short* __restrict__ C,
    int M, int K, int N,
    const int* __restrict__ lflag, const unsigned short* __restrict__ Wlab,
    const float* __restrict__ bias, const float* __restrict__ dinv) {
    __shared__ __align__(16) unsigned short lsA[64 * 64];     // 8 KB
    __shared__ __align__(16) unsigned short lsB[256 * 64];    // 32 KB
    const int t = threadIdx.x;
    const int wv = t >> 6, lane = t & 63;
    const int l16 = lane & 15, lk = lane >> 4;
    const int row0 = blockIdx.x * 64;
    const int col0 = blockIdx.y * 256;

    f32x4 acc[4][4];
    const f32x4 fz = {0.f, 0.f, 0.f, 0.f};
    #pragma unroll
    for (int m = 0; m < 4; ++m)
        #pragma unroll
        for (int n = 0; n < 4; ++n) acc[m][n] = fz;

    for (int k0 = 0; k0 < K; k0 += 64) {
        // ---- stage A (64 rows x 64 k = 512 chunks of 16 B)
        if (AF32) {
            #pragma unroll
            for (int q = 0; q < 2; ++q) {
                const int c = q * 256 + t;
                const int row = c >> 3;
                const int kg = (c & 7) ^ (row & 7);
                const int arow = min(row0 + row, M - 1);
                const float* src = Af + (size_t)arow * K + k0 + kg * 8;
                float4 f0 = *(const float4*)src;
                float4 f1 = *(const float4*)(src + 4);
                bf16x8 p;
                p[0] = (short)f2bf(f0.x); p[1] = (short)f2bf(f0.y);
                p[2] = (short)f2bf(f0.z); p[3] = (short)f2bf(f0.w);
                p[4] = (short)f2bf(f1.x); p[5] = (short)f2bf(f1.y);
                p[6] = (short)f2bf(f1.z); p[7] = (short)f2bf(f1.w);
                *(bf16x8*)&lsA[(size_t)c * 8] = p;
            }
        } else {
            #pragma unroll
            for (int q = 0; q < 2; ++q) {
                const int bc = q * 256 + wv * 64;
                const int c = bc + lane;
                const int row = c >> 3;
                const int kg = (c & 7) ^ (row & 7);
                const int arow = min(row0 + row, M - 1);
                gload_lds16(A + (size_t)arow * K + k0 + kg * 8, &lsA[(size_t)bc * 8]);
            }
        }
        // ---- stage B (256 out-cols x 64 k = 2048 chunks); Bt is [N][K]
        #pragma unroll
        for (int q = 0; q < 8; ++q) {
            const int bc = q * 256 + wv * 64;
            const int c = bc + lane;
            const int row = c >> 3;
            const int kg = (c & 7) ^ (row & 7);
            gload_lds16(Bt + (size_t)(col0 + row) * K + k0 + kg * 8, &lsB[(size_t)bc * 8]);
        }
        __syncthreads();
        #pragma unroll
        for (int kk = 0; kk < 2; ++kk) {
            bf16x8 a[4], b[4];
            #pragma unroll
            for (int m = 0; m < 4; ++m) {
                const int row = m * 16 + l16;
                const int cc = row * 8 + ((kk * 4 + lk) ^ (row & 7));
                a[m] = *(const bf16x8*)&lsA[(size_t)cc * 8];
            }
            #pragma unroll
            for (int n = 0; n < 4; ++n) {
                const int row = wv * 64 + n * 16 + l16;
                const int cc = row * 8 + ((kk * 4 + lk) ^ (row & 7));
                b[n] = *(const bf16x8*)&lsB[(size_t)cc * 8];
            }
            #pragma unroll
            for (int m = 0; m < 4; ++m)
                #pragma unroll
                for (int n = 0; n < 4; ++n)
                    acc[m][n] = __builtin_amdgcn_mfma_f32_16x16x32_bf16(a[m], b[n], acc[m][n], 0, 0, 0);
        }
        __syncthreads();
    }

    // epilogue: C/D layout col=lane&15, row=(lane>>4)*4+reg
    #pragma unroll
    for (int m = 0; m < 4; ++m) {
        #pragma unroll
        for (int r = 0; r < 4; ++r) {
            const int grow = row0 + m * 16 + lk * 4 + r;
            if (grow >= M) continue;
            float dv = 1.0f;
            if (EPI <= 1) dv = dinv[grow];
            int flag = -1;
            if (EPI == 1) flag = lflag[grow];
            #pragma unroll
            for (int n = 0; n < 4; ++n) {
                const int gcol = col0 + wv * 64 + n * 16 + l16;
                float v = acc[m][n][r];
                if (EPI == 1) { if (flag >= 0) v += bf2f(Wlab[flag * NHID + gcol]); }
                if (EPI <= 1) { v *= dv; }
                if (EPI == 2) { v += bias[gcol]; v = v > 0.f ? v : expm1f(v); }
                C[(size_t)grow * N + gcol] = f2bf(v);
            }
        }
    }
}

// ---------------- per-node aggregation (pure sum of pre-scaled Zs) ----------------
// H[d] = relu(dinv[d]*(sum_{e in edges(d)} Zs[src] + 2*Zs[d]) + b)
// 2 waves per node (column halves), 4 edges in flight per wave-iteration,
// 16-B lane loads. Cross-group reduce via shfl_xor.

__global__ __launch_bounds__(256) void agg_bf16(
    const unsigned short* __restrict__ Zs, const int* __restrict__ start,
    const int* __restrict__ ssrc, const float* __restrict__ dinv,
    const float* __restrict__ bias, unsigned short* __restrict__ H, int M) {
    const int t = threadIdx.x;
    const int wv = t >> 6, lane = t & 63;
    const int node = blockIdx.x * 2 + (wv >> 1);
    if (node >= M) return;
    const int half = wv & 1;
    const int g = lane >> 4, cl = lane & 15;
    const int c0 = half * 128 + cl * 8;

    float a[8] = {0.f, 0.f, 0.f, 0.f, 0.f, 0.f, 0.f, 0.f};
    const int s = start[node], e = start[node + 1];
    for (int base = s; base < e; base += 4) {
        const int idx = base + g;
        if (idx < e) {
            const int src = ssrc[idx];
            u16x8 z = *(const u16x8*)&Zs[(size_t)src * NHID + c0];
            #pragma unroll
            for (int j = 0; j < 8; ++j) a[j] += bf2f(z[j]);
        }
    }
    #pragma unroll
    for (int j = 0; j < 8; ++j) {
        a[j] += __shfl_xor(a[j], 16);
        a[j] += __shfl_xor(a[j], 32);
    }
    if (g == 0) {
        u16x8 zs = *(const u16x8*)&Zs[(size_t)node * NHID + c0];
        const float dv = dinv[node];
        float4 bb0 = *(const float4*)&bias[c0];
        float4 bb1 = *(const float4*)&bias[c0 + 4];
        float bbf[8] = {bb0.x, bb0.y, bb0.z, bb0.w, bb1.x, bb1.y, bb1.z, bb1.w};
        u16x8 o;
        #pragma unroll
        for (int j = 0; j < 8; ++j) {
            float v = dv * (a[j] + 2.0f * bf2f(zs[j])) + bbf[j];
            o[j] = f2bf(fmaxf(v, 0.f));
        }
        *(u16x8*)&H[(size_t)node * NHID + c0] = o;
    }
}

// ---------------- logits GEMM (M x 512 x 64) + fused log_softmax ----------------

__global__ __launch_bounds__(256) void logits_kernel(
    const unsigned short* __restrict__ A, const unsigned short* __restrict__ Bt,
    const float* __restrict__ bias, float* __restrict__ out, int M) {
    __shared__ __align__(16) unsigned short lsA[128 * 64];
    __shared__ __align__(16) unsigned short lsB[64 * 64];
    const int t = threadIdx.x;
    const int wv = t >> 6, lane = t & 63;
    const int l16 = lane & 15, lk = lane >> 4;
    const int row0 = blockIdx.x * 128;

    f32x4 acc[2][4];
    const f32x4 fz = {0.f, 0.f, 0.f, 0.f};
    #pragma unroll
    for (int m = 0; m < 2; ++m)
        #pragma unroll
        for (int n = 0; n < 4; ++n) acc[m][n] = fz;

    for (int k0 = 0; k0 < 512; k0 += 64) {
        #pragma unroll
        for (int q = 0; q < 4; ++q) {
            const int bc = wv * 256 + q * 64;
            const int c = bc + lane;
            const int row = c >> 3;
            const int kg = (c & 7) ^ (row & 7);
            gload_lds16(A + (size_t)min(row0 + row, M - 1) * 512 + k0 + kg * 8,
                        &lsA[(size_t)bc * 8]);
        }
        #pragma unroll
        for (int q = 0; q < 2; ++q) {
            const int bc = wv * 128 + q * 64;
            const int c = bc + lane;
            const int row = c >> 3;
            const int kg = (c & 7) ^ (row & 7);
            gload_lds16(Bt + (size_t)row * 512 + k0 + kg * 8, &lsB[(size_t)bc * 8]);
        }
        __syncthreads();
        #pragma unroll
        for (int kk = 0; kk < 2; ++kk) {
            bf16x8 a[2], b[4];
            #pragma unroll
            for (int m = 0; m < 2; ++m) {
                const int row = wv * 32 + m * 16 + l16;
                const int cc = row * 8 + ((kk * 4 + lk) ^ (row & 7));
                a[m] = *(const bf16x8*)&lsA[(size_t)cc * 8];
            }
            #pragma unroll
            for (int n = 0; n < 4; ++n) {
                const int row = n * 16 + l16;
                const int cc = row * 8 + ((kk * 4 + lk) ^ (row & 7));
                b[n] = *(const bf16x8*)&lsB[(size_t)cc * 8];
            }
            #pragma unroll
            for (int m = 0; m < 2; ++m)
                #pragma unroll
                for (int n = 0; n < 4; ++n)
                    acc[m][n] = __builtin_amdgcn_mfma_f32_16x16x32_bf16(a[m], b[n], acc[m][n], 0, 0, 0);
        }
        __syncthreads();
    }

    #pragma unroll
    for (int m = 0; m < 2; ++m) {
        #pragma unroll
        for (int r = 0; r < 4; ++r) {
            const int grow = row0 + wv * 32 + m * 16 + lk * 4 + r;
            float v[4];
            float mx = -3.4e38f;
            #pragma unroll
            for (int n = 0; n < 4; ++n) {
                v[n] = acc[m][n][r] + bias[n * 16 + l16];
                mx = fmaxf(mx, v[n]);
            }
            #pragma unroll
            for (int off = 1; off < 16; off <<= 1) mx = fmaxf(mx, __shfl_xor(mx, off));
            float s = 0.f;
            #pragma unroll
            for (int n = 0; n < 4; ++n) s += expf(v[n] - mx);
            #pragma unroll
            for (int off = 1; off < 16; off <<= 1) s += __shfl_xor(s, off);
            const float ls = logf(s);
            if (grow < M) {
                #pragma unroll
                for (int n = 0; n < 4; ++n)
                    out[(size_t)grow * NLAB + n * 16 + l16] = v[n] - mx - ls;
            }
        }
    }
}

// ---------------- launch ----------------

extern "C" void kernel_launch(void* const* d_in, const int* in_sizes, int n_in,
                              void* d_out, int out_size, void* d_ws, size_t ws_size,
                              hipStream_t stream) {
    const float* x   = (const float*)d_in[0];
    const int*   y   = (const int*)  d_in[1];
    const int*   adj = (const int*)  d_in[3];
    const int*   idxl= (const int*)  d_in[4];
    const float* W0  = (const float*)d_in[6];
    const float* b0  = (const float*)d_in[7];
    const float* W1  = (const float*)d_in[8];
    const float* b1  = (const float*)d_in[9];
    const float* W2  = (const float*)d_in[10];
    const float* b2  = (const float*)d_in[11];
    const float* Wm0 = (const float*)d_in[12];
    const float* bm0 = (const float*)d_in[13];
    const float* Wm1 = (const float*)d_in[14];
    const float* bm1 = (const float*)d_in[15];

    const int N = in_sizes[0] / NFEAT;
    const int E = in_sizes[3] / 2;
    const int L = in_sizes[4];
    const int* erow = adj;       // message sources
    const int* ecol = adj + E;   // aggregation targets

    char* ws = (char*)d_ws;
    size_t off = 0;
    auto alloc = [&](size_t bytes) -> void* {
        void* p = ws + off;
        off += (bytes + 255) & ~(size_t)255;
        return p;
    };
    const int P = N + 1;
    const int nb1 = (P + 1023) / 1024;
    unsigned short* Zb    = (unsigned short*)alloc((size_t)N * NHID * 2);
    unsigned short* Hb    = (unsigned short*)alloc((size_t)N * NHID * 2);
    int*   hist   = (int*)  alloc((size_t)N * 4);
    int*   startA = (int*)  alloc((size_t)nb1 * 1024 * 4);
    int*   cursor = (int*)  alloc((size_t)N * 4);
    float* dinv   = (float*)alloc((size_t)N * 4);
    int*   lflag  = (int*)  alloc((size_t)N * 4);
    int*   ssrc   = (int*)  alloc((size_t)E * 4);
    int*   bsum   = (int*)  alloc((size_t)1024 * 4);
    unsigned short* W0t   = (unsigned short*)alloc((size_t)256 * 512 * 2);
    unsigned short* W0lab = (unsigned short*)alloc((size_t)64 * 256 * 2);
    unsigned short* W1t   = (unsigned short*)alloc((size_t)256 * 256 * 2);
    unsigned short* W2t   = (unsigned short*)alloc((size_t)256 * 256 * 2);
    unsigned short* Wm0t  = (unsigned short*)alloc((size_t)512 * 256 * 2);
    unsigned short* Wm1t  = (unsigned short*)alloc((size_t)64 * 512 * 2);
    // H1 (M x 512 bf16): prefer ws; fall back to the (dead-after-layer-0) x buffer
    unsigned short* H1;
    {
        size_t need = (size_t)N * 512 * 2;
        if (off + need <= ws_size) H1 = (unsigned short*)alloc(need);
        else                       H1 = (unsigned short*)(void*)d_in[0];
    }

    hipMemsetAsync(hist, 0, (size_t)N * 4, stream);
    hipMemsetAsync(lflag, 0xFF, (size_t)N * 4, stream);   // -1

    const int TB = 256;
    hist_kernel<<<(E + TB - 1) / TB, TB, 0, stream>>>(ecol, hist, E);
    dinv_kernel<<<(N + TB - 1) / TB, TB, 0, stream>>>(hist, dinv, N);
    scan1_kernel<<<nb1, 1024, 0, stream>>>(hist, startA, bsum, N);
    scan2_kernel<<<1, 1024, 0, stream>>>(bsum, nb1);
    scan3_kernel<<<(P + TB - 1) / TB, TB, 0, stream>>>(startA, cursor, bsum, P);
    scatter_kernel<<<(E + TB - 1) / TB, TB, 0, stream>>>(erow, ecol, cursor, ssrc, E);
    labflag_kernel<<<(L + TB - 1) / TB, TB, 0, stream>>>(idxl, y, lflag, L);

    convT_kernel<<<(512 * 256 + TB - 1) / TB, TB, 0, stream>>>(W0, W0t, 512, 256);
    conv_kernel <<<(64 * 256 + TB - 1) / TB, TB, 0, stream>>>(W0 + (size_t)512 * 256, W0lab, 64 * 256);
    convT_kernel<<<(256 * 256 + TB - 1) / TB, TB, 0, stream>>>(W1, W1t, 256, 256);
    convT_kernel<<<(256 * 256 + TB - 1) / TB, TB, 0, stream>>>(W2, W2t, 256, 256);
    convT_kernel<<<(256 * 512 + TB - 1) / TB, TB, 0, stream>>>(Wm0, Wm0t, 256, 512);
    convT_kernel<<<(512 * 64 + TB - 1) / TB, TB, 0, stream>>>(Wm1, Wm1t, 512, 64);

    const int MB = (N + 63) / 64;
    dim3 g1(MB, 1), gH(MB, 2);
    const int aggGrid = (N + 1) / 2;
    // layer 0 (A = x fp32, K=512, + label rows, Zs = dinv*Z)
    mfma_gemm<1, true ><<<g1, 256, 0, stream>>>(nullptr, x, W0t, Zb, N, 512, 256, lflag, W0lab, nullptr, dinv);
    agg_bf16<<<aggGrid, 256, 0, stream>>>(Zb, startA, ssrc, dinv, b0, Hb, N);
    // layer 1
    mfma_gemm<0, false><<<g1, 256, 0, stream>>>(Hb, nullptr, W1t, Zb, N, 256, 256, nullptr, nullptr, nullptr, dinv);
    agg_bf16<<<aggGrid, 256, 0, stream>>>(Zb, startA, ssrc, dinv, b1, Hb, N);
    // layer 2
    mfma_gemm<0, false><<<g1, 256, 0, stream>>>(Hb, nullptr, W2t, Zb, N, 256, 256, nullptr, nullptr, nullptr, dinv);
    agg_bf16<<<aggGrid, 256, 0, stream>>>(Zb, startA, ssrc, dinv, b2, Hb, N);
    // MLP hidden: H1 = elu(Hb @ Wm0 + bm0), N=512
    mfma_gemm<2, false><<<gH, 256, 0, stream>>>(Hb, nullptr, Wm0t, H1, N, 256, 512, nullptr, nullptr, bm0, nullptr);
    // logits + log_softmax
    logits_kernel<<<(N + 127) / 128, 256, 0, stream>>>(H1, Wm1t, bm1, (float*)d_out, N);
}